// Round 5
// baseline (1560.875 us; speedup 1.0000x reference)
//
#include <hip/hip_runtime.h>

// RecursiveLSTM: B=1024, T=96, H=50, num_pred=12.
// Rounds 1-4 lesson: the compiler will NOT keep 50 per-thread weight floats
// resident across the barriered step loop (sinks/spills them; 160 KB/CU/step
// of L1 weight re-reads dominated). Fix is structural: NB=4 batch elements
// per block (grid=256 -> 1 block/CU), weights staged once in LDS in a
// k4-interleaved [k4][gate][4] layout (conflict-free ds_read_b128), each
// weight read ONCE per step and reused for 4 FMAs (one per batch).
// Per-thread state ~40 VGPRs -> nothing for the RA to sabotage.
// h: wave-private, batch-interleaved float4 (uniform broadcast reads, write
// as one b128) -> no barrier for h. Gates double-buffered -> 1 barrier/step.

#define HSZ   50
#define G4    200      // 4*H gates
#define TLEN  96
#define MAXP  16       // >= num_pred
#define NB    4        // batch elements per block

__device__ __forceinline__ float tanh_(float x) {
    // 1 - 2/(exp(2x)+1): no inf/inf NaN at large |x|
    return 1.0f - 2.0f / (__expf(2.0f * x) + 1.0f);
}
// a = m*sigmoid(m*acc) + (1-m): m=1 -> sigmoid, m=2 -> tanh
__device__ __forceinline__ float gatefn_(float a, float m, float add) {
    const float s = 1.0f / (1.0f + __expf(-m * a));
    return fmaf(m, s, add);
}

__global__ __launch_bounds__(256)
void rec_lstm_kernel(const float* __restrict__ x,
                     const float* __restrict__ W_ih,
                     const float* __restrict__ W_hh,
                     const float* __restrict__ b_ih,
                     const float* __restrict__ b_hh,
                     const float* __restrict__ W_fc,
                     const float* __restrict__ b_fc,
                     const int*   __restrict__ num_pred,
                     float*       __restrict__ out)
{
    const int  tid  = threadIdx.x;
    const int  wave = tid >> 6;
    const int  lane = tid & 63;
    const bool act  = (lane < HSZ);
    const int  g    = wave * HSZ + (act ? lane : HSZ - 1);  // gate owned; wave==gate type
    const int  b0   = blockIdx.x * NB;

    __shared__ __align__(16) float W4[13][G4][4];        // W4[k4][g][kk]=W_hh[g][4k4+kk]
    __shared__ __align__(16) float hb[4][13][4][4];      // per-wave h: [wave][k4][kk][batch]
    __shared__ float gl5[2][G4 * 5];                     // gates, stride 5 (bank-spread)
    __shared__ __align__(16) float xp4[(TLEN + MAXP) * 4]; // x ++ preds, batch-interleaved

    // ---- one-time staging ----
    for (int i = tid; i < 13 * G4 * 4; i += 256) {
        const int k4 = i / (G4 * 4), r = i % (G4 * 4), gg = r >> 2, kk = r & 3;
        const int k  = 4 * k4 + kk;
        W4[k4][gg][kk] = (k < HSZ) ? W_hh[gg * HSZ + k] : 0.f;
    }
    for (int i = tid; i < NB * TLEN; i += 256) {
        const int bb = i / TLEN, t = i % TLEN;
        xp4[t * 4 + bb] = x[(b0 + bb) * TLEN + t];
    }
    const float wih  = W_ih[g];
    const float bsum = b_ih[g] + b_hh[g];
    const float wfc  = act ? W_fc[lane] : 0.f;
    const float bfc  = b_fc[0];
    const int   NP   = num_pred[0];
    const float m_   = (wave == 2) ? 2.f : 1.f;   // wave 2 owns g-gates -> tanh
    const float add_ = 1.f - m_;

    __syncthreads();

    int par = 0;
    for (int p = 0; p < NP; ++p) {
        float c0 = 0.f, c1 = 0.f, c2 = 0.f, c3 = 0.f;   // cell state, 4 batches
        if (lane < 52) {                                 // zero wave-private h (+pad)
            *(float4*)&hb[wave][lane >> 2][lane & 3][0] = make_float4(0.f, 0.f, 0.f, 0.f);
        }
        // hb is wave-private: no barrier needed

        for (int t = 0; t < TLEN; ++t) {
            const float4 xv = *(const float4*)&xp4[(p + t) * 4];  // uniform broadcast
            float a0 = fmaf(wih, xv.x, bsum);
            float a1 = fmaf(wih, xv.y, bsum);
            float a2 = fmaf(wih, xv.z, bsum);
            float a3 = fmaf(wih, xv.w, bsum);
            #pragma unroll
            for (int k4 = 0; k4 < 13; ++k4) {
                const float4 w4 = *(const float4*)&W4[k4][g][0];          // b128, conflict-free
                const float4 h0 = *(const float4*)&hb[wave][k4][0][0];    // uniform broadcasts
                const float4 h1 = *(const float4*)&hb[wave][k4][1][0];
                const float4 h2 = *(const float4*)&hb[wave][k4][2][0];
                const float4 h3 = *(const float4*)&hb[wave][k4][3][0];
                a0 = fmaf(w4.x, h0.x, a0); a1 = fmaf(w4.x, h0.y, a1);
                a2 = fmaf(w4.x, h0.z, a2); a3 = fmaf(w4.x, h0.w, a3);
                a0 = fmaf(w4.y, h1.x, a0); a1 = fmaf(w4.y, h1.y, a1);
                a2 = fmaf(w4.y, h1.z, a2); a3 = fmaf(w4.y, h1.w, a3);
                a0 = fmaf(w4.z, h2.x, a0); a1 = fmaf(w4.z, h2.y, a1);
                a2 = fmaf(w4.z, h2.z, a2); a3 = fmaf(w4.z, h2.w, a3);
                a0 = fmaf(w4.w, h3.x, a0); a1 = fmaf(w4.w, h3.y, a1);
                a2 = fmaf(w4.w, h3.z, a2); a3 = fmaf(w4.w, h3.w, a3);
            }
            if (act) {
                const int gb = g * 5;                    // stride-5: gcd(5,32)=1, no conflicts
                gl5[par][gb + 0] = gatefn_(a0, m_, add_);
                gl5[par][gb + 1] = gatefn_(a1, m_, add_);
                gl5[par][gb + 2] = gatefn_(a2, m_, add_);
                gl5[par][gb + 3] = gatefn_(a3, m_, add_);
            }
            __syncthreads();                             // the ONE barrier per step

            if (act) {   // redundant per-wave update of unit j=lane, all 4 batches
                const int j5 = lane * 5;
                const float i0 = gl5[par][j5 +   0], i1 = gl5[par][j5 +   1],
                            i2 = gl5[par][j5 +   2], i3 = gl5[par][j5 +   3];
                const float f0 = gl5[par][j5 + 250], f1 = gl5[par][j5 + 251],
                            f2 = gl5[par][j5 + 252], f3 = gl5[par][j5 + 253];
                const float g0 = gl5[par][j5 + 500], g1 = gl5[par][j5 + 501],
                            g2 = gl5[par][j5 + 502], g3 = gl5[par][j5 + 503];
                const float o0 = gl5[par][j5 + 750], o1 = gl5[par][j5 + 751],
                            o2 = gl5[par][j5 + 752], o3 = gl5[par][j5 + 753];
                c0 = fmaf(f0, c0, i0 * g0);
                c1 = fmaf(f1, c1, i1 * g1);
                c2 = fmaf(f2, c2, i2 * g2);
                c3 = fmaf(f3, c3, i3 * g3);
                const float4 hv = make_float4(o0 * tanh_(c0), o1 * tanh_(c1),
                                              o2 * tanh_(c2), o3 * tanh_(c3));
                *(float4*)&hb[wave][lane >> 2][lane & 3][0] = hv;   // b128, conflict-free
            }
            par ^= 1;
        }

        // ---- FC head: wave w reduces batch w (4 reductions in parallel) ----
        float v = act ? hb[wave][lane >> 2][lane & 3][wave] * wfc : 0.f;
        #pragma unroll
        for (int off = 32; off >= 1; off >>= 1) v += __shfl_down(v, off, 64);
        if (lane == 0) {
            const float pr = v + bfc;
            xp4[(TLEN + p) * 4 + wave] = pr;     // feedback as next input
            out[(b0 + wave) * NP + p] = pr;
        }
        // no barrier needed: first read of xp4[TLEN+p] is >=84 per-step
        // barriers later, which orders it after this write.
    }
}

extern "C" void kernel_launch(void* const* d_in, const int* in_sizes, int n_in,
                              void* d_out, int out_size, void* d_ws, size_t ws_size,
                              hipStream_t stream)
{
    const float* x    = (const float*)d_in[0];
    const float* W_ih = (const float*)d_in[1];
    const float* W_hh = (const float*)d_in[2];
    const float* b_ih = (const float*)d_in[3];
    const float* b_hh = (const float*)d_in[4];
    const float* W_fc = (const float*)d_in[5];
    const float* b_fc = (const float*)d_in[6];
    const int*   np   = (const int*)d_in[7];
    float* out = (float*)d_out;

    const int B = in_sizes[0] / TLEN;   // 1024
    rec_lstm_kernel<<<B / NB, 256, 0, stream>>>(x, W_ih, W_hh, b_ih, b_hh,
                                                W_fc, b_fc, np, out);
}